// Round 4
// baseline (149.752 us; speedup 1.0000x reference)
//
#include <hip/hip_runtime.h>

#define BATCH   1024
#define GROUPS  512
#define OUT_DIM 64

// LDS geometry: 4 tables per block; row = 64 data words + 4 pad (68);
// table stride = 16*68 + 4 = 1092 words (phase-staggers tables by 4 banks).
#define ROW_WORDS 68
#define TBL_WORDS 1092

// Block = (g-quad, 64-batch chunk). Wave lanes = 4 g x 16 float4-cols; each
// wave iterates 16 consecutive b. Properties:
//  - store: out[b][g0..g0+3][0..63] = one contiguous 1 KiB per wave-instr
//  - X load: (b*512+g0)*16 with g0%4==0 -> exactly one 64 B line per iter,
//    each line fetched once globally (no overfetch)
//  - LDS: per b128 read, each j-group's t*4+w sweep covers all 32 banks
//    uniformly -> structural minimum cycles, no excess conflicts
__global__ __launch_bounds__(256) void hoact_kernel(
    const float4* __restrict__ X4,   // [B*G]     (4 f32 -> one float4)
    const float4* __restrict__ P4,   // [G*256]   (16 rows x 16 float4)
    float4*       __restrict__ O4)   // [B*G*16]
{
    __shared__ float tbl[4 * TBL_WORDS];

    const int gq  = blockIdx.x & 127;        // g-quad index 0..127
    const int bc  = blockIdx.x >> 7;         // b-chunk 0..15
    const int g0  = gq * 4;
    const int b0  = bc * 64;
    const int tid = threadIdx.x;             // 0..255

    // ---- stage params[g0..g0+3] into LDS (coalesced 16 KiB global read) ----
#pragma unroll
    for (int i0 = 0; i0 < 1024; i0 += 256) {
        const int i = i0 + tid;
        const float4 v = P4[g0 * 256 + i];
        const int j   = i >> 8;              // which table
        const int rc  = i & 255;
        const int row = rc >> 4, c4 = rc & 15;
        *(float4*)&tbl[j * TBL_WORDS + row * ROW_WORDS + c4 * 4] = v;
    }

    const int lane  = tid & 63;
    const int wv    = tid >> 6;              // wave 0..3
    const int j     = lane >> 4;             // g within quad
    const int t     = lane & 15;             // float4 column within D=64
    const int g     = g0 + j;
    const int tbase = j * TBL_WORDS;
    const int bb    = b0 + wv * 16;          // this wave's 16 consecutive b

    __syncthreads();

    float4 xv = X4[bb * GROUPS + g];         // prefetch iter 0

#pragma unroll
    for (int it = 0; it < 16; ++it) {
        const int b = bb + it;
        float4 xn;
        if (it < 15) xn = X4[(b + 1) * GROUPS + g];  // prefetch next iter

        // pack 2-bit source index into mantissa LSBs (<=3 ULP, harmless vs
        // 0.485 threshold); fmin/fmax sort network; ties -> zero gap coef.
        float v0 = __uint_as_float((__float_as_uint(xv.x) & ~3u) | 0u);
        float v1 = __uint_as_float((__float_as_uint(xv.y) & ~3u) | 1u);
        float v2 = __uint_as_float((__float_as_uint(xv.z) & ~3u) | 2u);
        float v3 = __uint_as_float((__float_as_uint(xv.w) & ~3u) | 3u);

#define CSWAP(a, b_)                                 \
        {                                            \
            const float lo = fminf((a), (b_));       \
            const float hi = fmaxf((a), (b_));       \
            (a) = lo; (b_) = hi;                     \
        }
        CSWAP(v0, v1);
        CSWAP(v2, v3);
        CSWAP(v0, v2);
        CSWAP(v1, v3);
        CSWAP(v1, v2);
#undef CSWAP

        const int i1 = __float_as_uint(v1) & 3;
        const int i2 = __float_as_uint(v2) & 3;
        const int i3 = __float_as_uint(v3) & 3;

        const float c0 = v0;
        const float c1 = v1 - v0;
        const float c2 = v2 - v1;
        const float c3 = v3 - v2;

        const int e3 = 1 << i3;
        const int e2 = e3 + (1 << i2);
        const int e1 = e2 + (1 << i1);
        // e0 == 15 always

        const float4 p0 = *(const float4*)&tbl[tbase + 15 * ROW_WORDS + t * 4];
        const float4 p1 = *(const float4*)&tbl[tbase + e1 * ROW_WORDS + t * 4];
        const float4 p2 = *(const float4*)&tbl[tbase + e2 * ROW_WORDS + t * 4];
        const float4 p3 = *(const float4*)&tbl[tbase + e3 * ROW_WORDS + t * 4];

        float4 o;
        o.x = c0 * p0.x + c1 * p1.x + c2 * p2.x + c3 * p3.x;
        o.y = c0 * p0.y + c1 * p1.y + c2 * p2.y + c3 * p3.y;
        o.z = c0 * p0.z + c1 * p1.z + c2 * p2.z + c3 * p3.z;
        o.w = c0 * p0.w + c1 * p1.w + c2 * p2.w + c3 * p3.w;

        // lane index j*16+t == lane -> wave writes one contiguous 1 KiB run
        O4[b * (GROUPS * 16) + g * 16 + t] = o;

        xv = xn;
    }
}

extern "C" void kernel_launch(void* const* d_in, const int* in_sizes, int n_in,
                              void* d_out, int out_size, void* d_ws, size_t ws_size,
                              hipStream_t stream) {
    const float4* X4 = (const float4*)d_in[0];   // X: [1024, 512, 4] fp32
    const float4* P4 = (const float4*)d_in[1];   // params: [512, 16, 64] fp32
    float4*       O4 = (float4*)d_out;           // out: [1024, 512, 64] fp32

    const int grid = 128 * 16;                   // 2048 blocks
    hipLaunchKernelGGL(hoact_kernel, dim3(grid), dim3(256), 0, stream,
                       X4, P4, O4);
}

// Round 6
// 149.205 us; speedup vs baseline: 1.0037x; 1.0037x over previous
//
#include <hip/hip_runtime.h>

#define BATCH   1024
#define GROUPS  512
#define OUT_DIM 64

// LDS table geometry: row = 64 data words + 4 pad (68); table stride
// 16*68+4 = 1092 words staggers the 4 tables' bank phase by 4.
#define ROW_WORDS 68
#define TBL_WORDS 1092

// native 4-float vector for __builtin_nontemporal_store (HIP float4 is a
// class and is rejected by the builtin)
typedef float floatx4 __attribute__((ext_vector_type(4)));

// Block = (g-quad, 64-batch chunk), 2048 blocks, 256 threads.
//  - X slab (64 b x 4 g = 4 KiB) staged to LDS upfront, fully coalesced ->
//    NO global-load latency inside the loop (R4's mistake).
//  - params[g0..g0+3] staged to LDS (16 KiB coalesced read, ~17 KiB padded).
//  - wave lanes = 4 g x 16 float4-cols; store = one contiguous 1 KiB/instr.
//  - vertex-15 row is loop-invariant -> hoisted (3 ds_read_b128/iter, not 4).
//  - nontemporal stores: streaming output, keep L2 for the param tables.
__global__ __launch_bounds__(256) void hoact_kernel(
    const float4* __restrict__ X4,   // [B*G]     (4 f32 -> one float4)
    const float4* __restrict__ P4,   // [G*256]   (16 rows x 16 float4)
    float4*       __restrict__ O4)   // [B*G*16]
{
    __shared__ float  tbl[4 * TBL_WORDS];   // 17472 B
    __shared__ float4 xs[256];              //  4096 B

    const int gq  = blockIdx.x & 127;        // g-quad 0..127
    const int bc  = blockIdx.x >> 7;         // b-chunk 0..15
    const int g0  = gq * 4;
    const int b0  = bc * 64;
    const int tid = threadIdx.x;             // 0..255

    // ---- stage X[b0..b0+63][g0..g0+3] into LDS (one float4 per thread) ----
    {
        const int bl = tid >> 2, jj = tid & 3;   // 4 threads = one 64 B line
        xs[tid] = X4[(b0 + bl) * GROUPS + g0 + jj];
    }

    // ---- stage params[g0..g0+3] into LDS (contiguous 16 KiB global read) ----
#pragma unroll
    for (int i0 = 0; i0 < 1024; i0 += 256) {
        const int i  = i0 + tid;
        const float4 v = P4[g0 * 256 + i];
        const int j  = i >> 8;               // which table
        const int rc = i & 255;
        *(float4*)&tbl[j * TBL_WORDS + (rc >> 4) * ROW_WORDS + (rc & 15) * 4] = v;
    }

    const int lane  = tid & 63;
    const int wv    = tid >> 6;              // wave 0..3
    const int j     = lane >> 4;             // g within quad
    const int t     = lane & 15;             // float4 column within D=64
    const int g     = g0 + j;
    const int tbase = j * TBL_WORDS;

    __syncthreads();

    // vertex 15 (e0) row is the same every iteration -> hoist
    const float4 p0 = *(const float4*)&tbl[tbase + 15 * ROW_WORDS + t * 4];

    float4 xv = xs[(wv * 16) * 4 + j];       // prefetch iter 0 (LDS broadcast)

#pragma unroll
    for (int it = 0; it < 16; ++it) {
        const int b = b0 + wv * 16 + it;
        float4 xn;
        if (it < 15) xn = xs[(wv * 16 + it + 1) * 4 + j];

        // pack 2-bit source index into mantissa LSBs (<=3 ULP, harmless vs
        // 0.485 threshold); fmin/fmax sort network; ties -> zero gap coef.
        float v0 = __uint_as_float((__float_as_uint(xv.x) & ~3u) | 0u);
        float v1 = __uint_as_float((__float_as_uint(xv.y) & ~3u) | 1u);
        float v2 = __uint_as_float((__float_as_uint(xv.z) & ~3u) | 2u);
        float v3 = __uint_as_float((__float_as_uint(xv.w) & ~3u) | 3u);

#define CSWAP(a, b_)                                 \
        {                                            \
            const float lo = fminf((a), (b_));       \
            const float hi = fmaxf((a), (b_));       \
            (a) = lo; (b_) = hi;                     \
        }
        CSWAP(v0, v1);
        CSWAP(v2, v3);
        CSWAP(v0, v2);
        CSWAP(v1, v3);
        CSWAP(v1, v2);
#undef CSWAP

        const int i1 = __float_as_uint(v1) & 3;
        const int i2 = __float_as_uint(v2) & 3;
        const int i3 = __float_as_uint(v3) & 3;

        const float c0 = v0;
        const float c1 = v1 - v0;
        const float c2 = v2 - v1;
        const float c3 = v3 - v2;

        const int e3 = 1 << i3;
        const int e2 = e3 + (1 << i2);
        const int e1 = e2 + (1 << i1);

        const float4 p1 = *(const float4*)&tbl[tbase + e1 * ROW_WORDS + t * 4];
        const float4 p2 = *(const float4*)&tbl[tbase + e2 * ROW_WORDS + t * 4];
        const float4 p3 = *(const float4*)&tbl[tbase + e3 * ROW_WORDS + t * 4];

        floatx4 o;
        o.x = c0 * p0.x + c1 * p1.x + c2 * p2.x + c3 * p3.x;
        o.y = c0 * p0.y + c1 * p1.y + c2 * p2.y + c3 * p3.y;
        o.z = c0 * p0.z + c1 * p1.z + c2 * p2.z + c3 * p3.z;
        o.w = c0 * p0.w + c1 * p1.w + c2 * p2.w + c3 * p3.w;

        // lane == j*16+t -> wave writes one contiguous 1 KiB run
        __builtin_nontemporal_store(
            o, (floatx4*)&O4[b * (GROUPS * 16) + g * 16 + t]);

        xv = xn;
    }
}

extern "C" void kernel_launch(void* const* d_in, const int* in_sizes, int n_in,
                              void* d_out, int out_size, void* d_ws, size_t ws_size,
                              hipStream_t stream) {
    const float4* X4 = (const float4*)d_in[0];   // X: [1024, 512, 4] fp32
    const float4* P4 = (const float4*)d_in[1];   // params: [512, 16, 64] fp32
    float4*       O4 = (float4*)d_out;           // out: [1024, 512, 64] fp32

    const int grid = 128 * 16;                   // 2048 blocks
    hipLaunchKernelGGL(hoact_kernel, dim3(grid), dim3(256), 0, stream,
                       X4, P4, O4);
}